// Round 4
// baseline (416.094 us; speedup 1.0000x reference)
//
#include <hip/hip_runtime.h>

// GCN 2-layer GraphConv (norm='both'), fp32.
// Round 4: line-strided histograms (1 bin per 64B line -> 16x less same-line
//          RMW serialization), 1 edge/thread hist, compact deg[] for scan/pulls.
//
// ws layout (ints first, floats after):
//   int   hist_s[16N] | hist_d[16N]   <- strided bins; region reused as col[E]
//   int   deg[N], rowptr[N], bsum[1024]
//   float out_norm[N], in_norm[N], h1[64N] (alias h2[32N]),
//         agg1[64N] (alias int rank[E] during CSR build)

#define SCAN_BLK 1024  // elements per scan block (256 thr x 4)
#define HSTRIDE 16     // ints per histogram bin (64B line)

__global__ __launch_bounds__(256) void gcn_hist(const int* __restrict__ src,
                                                const int* __restrict__ dst,
                                                int* __restrict__ hist_s,
                                                int* __restrict__ hist_d,
                                                int* __restrict__ rank, int E) {
  int e = blockIdx.x * 256 + threadIdx.x;
  if (e < E) {
    atomicAdd(&hist_s[(size_t)src[e] * HSTRIDE], 1);
    rank[e] = atomicAdd(&hist_d[(size_t)dst[e] * HSTRIDE], 1);
  }
}

// read strided hists -> norms + compact deg
__global__ __launch_bounds__(256) void gcn_norm(const int* __restrict__ hist_s,
                                                const int* __restrict__ hist_d,
                                                float* __restrict__ out_norm,
                                                float* __restrict__ in_norm,
                                                int* __restrict__ deg, int n) {
  int i = blockIdx.x * 256 + threadIdx.x;
  if (i < n) {
    int ds = hist_s[(size_t)i * HSTRIDE];
    int dd = hist_d[(size_t)i * HSTRIDE];
    out_norm[i] = rsqrtf(fmaxf((float)ds, 1.0f));
    in_norm[i]  = rsqrtf(fmaxf((float)dd, 1.0f));
    deg[i] = dd;
  }
}

// ---- 3-kernel exclusive scan of deg -> rowptr ----
__global__ __launch_bounds__(256) void scan_local(const int* __restrict__ in,
                                                  int* __restrict__ out,
                                                  int* __restrict__ bsum, int n) {
  __shared__ int tmp[256];
  int t = threadIdx.x;
  int base = blockIdx.x * SCAN_BLK + t * 4;
  int v[4], s = 0;
#pragma unroll
  for (int i = 0; i < 4; i++) {
    v[i] = (base + i < n) ? in[base + i] : 0;
    s += v[i];
  }
  tmp[t] = s;
  __syncthreads();
#pragma unroll
  for (int off = 1; off < 256; off <<= 1) {
    int val = (t >= off) ? tmp[t - off] : 0;
    __syncthreads();
    tmp[t] += val;
    __syncthreads();
  }
  int run = tmp[t] - s;  // exclusive prefix
#pragma unroll
  for (int i = 0; i < 4; i++) {
    if (base + i < n) out[base + i] = run;
    run += v[i];
  }
  if (t == 255) bsum[blockIdx.x] = tmp[255];
}

__global__ __launch_bounds__(128) void scan_bsums(int* __restrict__ bsum, int nb) {
  __shared__ int tmp[128];
  int t = threadIdx.x;
  int v = (t < nb) ? bsum[t] : 0;
  tmp[t] = v;
  __syncthreads();
#pragma unroll
  for (int off = 1; off < 128; off <<= 1) {
    int val = (t >= off) ? tmp[t - off] : 0;
    __syncthreads();
    tmp[t] += val;
    __syncthreads();
  }
  if (t < nb) bsum[t] = tmp[t] - v;  // exclusive
}

__global__ __launch_bounds__(256) void scan_add(int* __restrict__ out,
                                                const int* __restrict__ bsum, int n) {
  int i = blockIdx.x * 256 + threadIdx.x;
  if (i < n) out[i] += bsum[i / SCAN_BLK];
}

// ---- CSR placement, atomic-free: col[rowptr[dst]+rank] = src ----
__global__ __launch_bounds__(256) void gcn_place(const int* __restrict__ src,
                                                 const int* __restrict__ dst,
                                                 const int* __restrict__ rowptr,
                                                 const int* __restrict__ rank,
                                                 int* __restrict__ col, int E) {
  int base = (blockIdx.x * 256 + threadIdx.x) * 4;
  if (base + 4 <= E) {
    int4 s4 = *(const int4*)(src + base);
    int4 d4 = *(const int4*)(dst + base);
    int4 r4 = *(const int4*)(rank + base);
    col[rowptr[d4.x] + r4.x] = s4.x;
    col[rowptr[d4.y] + r4.y] = s4.y;
    col[rowptr[d4.z] + r4.z] = s4.z;
    col[rowptr[d4.w] + r4.w] = s4.w;
  } else {
    for (int e = base; e < E; e++) col[rowptr[dst[e]] + rank[e]] = src[e];
  }
}

// ---- h1[N,64] = (x * out_norm[:,None]) @ W1[64,64] ----
__global__ __launch_bounds__(256) void gcn_xw1(const float* __restrict__ x,
                                               const float* __restrict__ W,
                                               const float* __restrict__ out_norm,
                                               float* __restrict__ h1, int n) {
  __shared__ float Ws[64 * 64];
  __shared__ float xs[16 * 64];
  int t = threadIdx.x;
#pragma unroll
  for (int i = 0; i < 16; i++) Ws[i * 256 + t] = W[i * 256 + t];
  int row0 = blockIdx.x * 16;
#pragma unroll
  for (int i = 0; i < 4; i++) {
    int idx = i * 256 + t;
    int r = idx >> 6, k = idx & 63;
    int row = row0 + r;
    xs[idx] = (row < n) ? x[row * 64 + k] * out_norm[row] : 0.0f;
  }
  __syncthreads();
  int c = t & 63, rq = t >> 6;
  float acc[4] = {0.f, 0.f, 0.f, 0.f};
#pragma unroll 16
  for (int k = 0; k < 64; k++) {
    float w = Ws[k * 64 + c];
#pragma unroll
    for (int rr = 0; rr < 4; rr++) acc[rr] += xs[(rq + rr * 4) * 64 + k] * w;
  }
#pragma unroll
  for (int rr = 0; rr < 4; rr++) {
    int row = row0 + rq + rr * 4;
    if (row < n) h1[row * 64 + c] = acc[rr];
  }
}

// ---- pull 64 feats: 1 wave/node; lane = (edge-slot 0..3, feat-quad 0..15)
__global__ __launch_bounds__(256) void gcn_pull64(const int* __restrict__ rowptr,
                                                  const int* __restrict__ deg,
                                                  const int* __restrict__ col,
                                                  const float* __restrict__ h,
                                                  float* __restrict__ agg, int n) {
  int t = threadIdx.x;
  int node = blockIdx.x * 4 + (t >> 6);
  if (node >= n) return;
  int l = t & 63;
  int sub = l >> 4;   // edge slot 0..3
  int fq  = l & 15;   // feature quad
  int beg = rowptr[node];
  int end = beg + deg[node];
  float4 a0 = {0, 0, 0, 0}, a1 = {0, 0, 0, 0};
  int j = beg;
  for (; j + 8 <= end; j += 8) {
    int s0 = col[j + sub];
    int s1 = col[j + 4 + sub];
    float4 v0 = ((const float4*)h)[(size_t)s0 * 16 + fq];
    float4 v1 = ((const float4*)h)[(size_t)s1 * 16 + fq];
    a0.x += v0.x; a0.y += v0.y; a0.z += v0.z; a0.w += v0.w;
    a1.x += v1.x; a1.y += v1.y; a1.z += v1.z; a1.w += v1.w;
  }
  for (; j < end; j += 4) {
    int jj = j + sub;
    if (jj < end) {
      int s = col[jj];
      float4 v = ((const float4*)h)[(size_t)s * 16 + fq];
      a0.x += v.x; a0.y += v.y; a0.z += v.z; a0.w += v.w;
    }
  }
  float4 acc;
  acc.x = a0.x + a1.x; acc.y = a0.y + a1.y; acc.z = a0.z + a1.z; acc.w = a0.w + a1.w;
#pragma unroll
  for (int d = 16; d <= 32; d <<= 1) {
    acc.x += __shfl_xor(acc.x, d);
    acc.y += __shfl_xor(acc.y, d);
    acc.z += __shfl_xor(acc.z, d);
    acc.w += __shfl_xor(acc.w, d);
  }
  if (sub == 0) ((float4*)agg)[(size_t)node * 16 + fq] = acc;
}

// ---- h2[N,32] = (relu(agg1 * in_norm + b1) * out_norm) @ W2[64,32] ----
__global__ __launch_bounds__(256) void gcn_xw2(const float* __restrict__ agg1,
                                               const float* __restrict__ W,
                                               const float* __restrict__ b1,
                                               const float* __restrict__ in_norm,
                                               const float* __restrict__ out_norm,
                                               float* __restrict__ h2, int n) {
  __shared__ float Ws[64 * 32];
  __shared__ float xs[16 * 64];
  int t = threadIdx.x;
#pragma unroll
  for (int i = 0; i < 8; i++) Ws[i * 256 + t] = W[i * 256 + t];
  int row0 = blockIdx.x * 16;
#pragma unroll
  for (int i = 0; i < 4; i++) {
    int idx = i * 256 + t;
    int r = idx >> 6, k = idx & 63;
    int row = row0 + r;
    float v = 0.0f;
    if (row < n)
      v = fmaxf(agg1[(size_t)row * 64 + k] * in_norm[row] + b1[k], 0.0f) * out_norm[row];
    xs[idx] = v;
  }
  __syncthreads();
  int c = t & 31, rq = t >> 5;
  float acc0 = 0.f, acc1 = 0.f;
#pragma unroll 16
  for (int k = 0; k < 64; k++) {
    float w = Ws[k * 32 + c];
    acc0 += xs[rq * 64 + k] * w;
    acc1 += xs[(rq + 8) * 64 + k] * w;
  }
  int row = row0 + rq;
  if (row < n) h2[(size_t)row * 32 + c] = acc0;
  row = row0 + rq + 8;
  if (row < n) h2[(size_t)row * 32 + c] = acc1;
}

// ---- pull 32 feats + fused epilogue: lane = (edge-slot 0..7, feat-quad 0..7)
__global__ __launch_bounds__(256) void gcn_pull32(const int* __restrict__ rowptr,
                                                  const int* __restrict__ deg,
                                                  const int* __restrict__ col,
                                                  const float* __restrict__ h,
                                                  const float* __restrict__ in_norm,
                                                  const float* __restrict__ b2,
                                                  float* __restrict__ out, int n) {
  int t = threadIdx.x;
  int node = blockIdx.x * 4 + (t >> 6);
  if (node >= n) return;
  int l = t & 63;
  int sub = l >> 3;   // edge slot 0..7
  int fq  = l & 7;    // feature quad 0..7
  int beg = rowptr[node];
  int end = beg + deg[node];
  float4 a0 = {0, 0, 0, 0}, a1 = {0, 0, 0, 0};
  int j = beg;
  for (; j + 16 <= end; j += 16) {
    int s0 = col[j + sub];
    int s1 = col[j + 8 + sub];
    float4 v0 = ((const float4*)h)[(size_t)s0 * 8 + fq];
    float4 v1 = ((const float4*)h)[(size_t)s1 * 8 + fq];
    a0.x += v0.x; a0.y += v0.y; a0.z += v0.z; a0.w += v0.w;
    a1.x += v1.x; a1.y += v1.y; a1.z += v1.z; a1.w += v1.w;
  }
  for (; j < end; j += 8) {
    int jj = j + sub;
    if (jj < end) {
      int s = col[jj];
      float4 v = ((const float4*)h)[(size_t)s * 8 + fq];
      a0.x += v.x; a0.y += v.y; a0.z += v.z; a0.w += v.w;
    }
  }
  float4 acc;
  acc.x = a0.x + a1.x; acc.y = a0.y + a1.y; acc.z = a0.z + a1.z; acc.w = a0.w + a1.w;
#pragma unroll
  for (int d = 8; d <= 32; d <<= 1) {
    acc.x += __shfl_xor(acc.x, d);
    acc.y += __shfl_xor(acc.y, d);
    acc.z += __shfl_xor(acc.z, d);
    acc.w += __shfl_xor(acc.w, d);
  }
  if (sub == 0) {
    float s = in_norm[node];
    float4 bb = ((const float4*)b2)[fq];
    acc.x = acc.x * s + bb.x;
    acc.y = acc.y * s + bb.y;
    acc.z = acc.z * s + bb.z;
    acc.w = acc.w * s + bb.w;
    ((float4*)out)[(size_t)node * 8 + fq] = acc;
  }
}

extern "C" void kernel_launch(void* const* d_in, const int* in_sizes, int n_in,
                              void* d_out, int out_size, void* d_ws, size_t ws_size,
                              hipStream_t stream) {
  const float* x   = (const float*)d_in[0];
  const int*   src = (const int*)d_in[1];
  const int*   dst = (const int*)d_in[2];
  const float* W1  = (const float*)d_in[3];
  const float* b1  = (const float*)d_in[4];
  const float* W2  = (const float*)d_in[5];
  const float* b2  = (const float*)d_in[6];
  float* out = (float*)d_out;

  const int N = in_sizes[0] / 64;   // 100000
  const int E = in_sizes[1];        // 1600000
  const int NB = (N + SCAN_BLK - 1) / SCAN_BLK;

  // strided hists: 16N ints each; region (32N ints) reused as col after norm.
  int* hist_s = (int*)d_ws;                       // 16N
  int* hist_d = hist_s + (size_t)HSTRIDE * N;     // 16N
  int* col    = hist_s;                           // E ints; E <= 32N required
  int* deg    = hist_d + (size_t)HSTRIDE * N;     // N
  int* rowptr = deg + N;                          // N
  int* bsum   = rowptr + N;                       // 1024
  float* out_norm = (float*)(bsum + 1024);        // N
  float* in_norm  = out_norm + N;                 // N
  float* h1       = in_norm + N;                  // 64N (alias h2: 32N)
  float* agg1     = h1 + (size_t)64 * N;          // 64N (alias rank[E])
  int*   rank     = (int*)agg1;                   // E ints; dead before pull64
  float* h2       = h1;                           // h1 dead after pull64

  // zero both strided histograms (contiguous 32N ints = 12.8MB)
  hipMemsetAsync(hist_s, 0, (size_t)2 * HSTRIDE * N * sizeof(int), stream);

  gcn_hist<<<(E + 255) / 256, 256, 0, stream>>>(src, dst, hist_s, hist_d, rank, E);
  gcn_norm<<<(N + 255) / 256, 256, 0, stream>>>(hist_s, hist_d, out_norm, in_norm, deg, N);
  scan_local<<<NB, 256, 0, stream>>>(deg, rowptr, bsum, N);
  scan_bsums<<<1, 128, 0, stream>>>(bsum, NB);
  scan_add<<<(N + 255) / 256, 256, 0, stream>>>(rowptr, bsum, N);
  int gE4 = (E / 4 + 255) / 256 + 1;
  gcn_place<<<gE4, 256, 0, stream>>>(src, dst, rowptr, rank, col, E);
  gcn_xw1<<<(N + 15) / 16, 256, 0, stream>>>(x, W1, out_norm, h1, N);
  gcn_pull64<<<(N + 3) / 4, 256, 0, stream>>>(rowptr, deg, col, h1, agg1, N);
  gcn_xw2<<<(N + 15) / 16, 256, 0, stream>>>(agg1, W2, b1, in_norm, out_norm, h2, N);
  gcn_pull32<<<(N + 3) / 4, 256, 0, stream>>>(rowptr, deg, col, h2, in_norm, b2, out, N);
}

// Round 5
// 337.023 us; speedup vs baseline: 1.2346x; 1.2346x over previous
//
#include <hip/hip_runtime.h>
#include <hip/hip_fp16.h>

// GCN 2-layer GraphConv (norm='both'), fp32 in/out, fp16 intermediates.
// Round 5: hist fused with (unscaled) xw1 to hide VALU work under the
//          ~20-26 G ops/s random-atomic ceiling; out_norm applied in pull64
//          gather; fp16 h1/h2 halve gather traffic; norm fused into scan.
//
// ws: int hist_s[N] | hist_d[N](=deg) | rowptr[N] | bsum[1024] | col[E]
//     float out_norm[N] | in_norm[N] | agg1[64N] (alias int rank[E])
//     half h1[64N] (alias h2[32N])

#define SCAN_BLK 1024

// ---- fused: histogram+rank (even-ish blocks) and h1 = x @ W1 (odd blocks) ----
__global__ __launch_bounds__(256) void fused_hist_xw1(
    const int* __restrict__ src, const int* __restrict__ dst,
    int* __restrict__ hist_s, int* __restrict__ hist_d, int* __restrict__ rank,
    const float* __restrict__ x, const float* __restrict__ W,
    __half* __restrict__ h1, int E, int n, int GH, int GX) {
  __shared__ float Ws[64 * 64];
  __shared__ float xs[16 * 64];
  int bid = blockIdx.x;
  int Mn = (GH < GX) ? GH : GX;
  bool isHist;
  int idx;
  if (bid < 2 * Mn) { isHist = !(bid & 1); idx = bid >> 1; }
  else               { isHist = (GH > GX); idx = bid - 2 * Mn + Mn; }

  if (isHist) {
    int e = idx * 256 + threadIdx.x;
    if (e < E) {
      atomicAdd(&hist_s[src[e]], 1);
      rank[e] = atomicAdd(&hist_d[dst[e]], 1);
    }
    return;
  }
  // xw1 role: h1[row,64] = x[row,:] @ W1 (no norm — applied in pull64)
  int t = threadIdx.x;
#pragma unroll
  for (int i = 0; i < 16; i++) Ws[i * 256 + t] = W[i * 256 + t];
  int row0 = idx * 16;
#pragma unroll
  for (int i = 0; i < 4; i++) {
    int gi = i * 256 + t;
    int r = gi >> 6, k = gi & 63;
    int row = row0 + r;
    xs[gi] = (row < n) ? x[row * 64 + k] : 0.0f;
  }
  __syncthreads();
  int c = t & 63, rq = t >> 6;
  float acc[4] = {0.f, 0.f, 0.f, 0.f};
#pragma unroll 16
  for (int k = 0; k < 64; k++) {
    float w = Ws[k * 64 + c];
#pragma unroll
    for (int rr = 0; rr < 4; rr++) acc[rr] += xs[(rq + rr * 4) * 64 + k] * w;
  }
#pragma unroll
  for (int rr = 0; rr < 4; rr++) {
    int row = row0 + rq + rr * 4;
    if (row < n) h1[(size_t)row * 64 + c] = __float2half(acc[rr]);
  }
}

// ---- scan of hist_d -> rowptr, fused with norm computation ----
__global__ __launch_bounds__(256) void scan_local(const int* __restrict__ hist_d,
                                                  const int* __restrict__ hist_s,
                                                  int* __restrict__ rowptr,
                                                  int* __restrict__ bsum,
                                                  float* __restrict__ out_norm,
                                                  float* __restrict__ in_norm, int n) {
  __shared__ int tmp[256];
  int t = threadIdx.x;
  int base = blockIdx.x * SCAN_BLK + t * 4;
  int v[4], s = 0;
#pragma unroll
  for (int i = 0; i < 4; i++) {
    v[i] = (base + i < n) ? hist_d[base + i] : 0;
    s += v[i];
  }
#pragma unroll
  for (int i = 0; i < 4; i++) {
    if (base + i < n) {
      in_norm[base + i] = rsqrtf(fmaxf((float)v[i], 1.0f));
      out_norm[base + i] = rsqrtf(fmaxf((float)hist_s[base + i], 1.0f));
    }
  }
  tmp[t] = s;
  __syncthreads();
#pragma unroll
  for (int off = 1; off < 256; off <<= 1) {
    int val = (t >= off) ? tmp[t - off] : 0;
    __syncthreads();
    tmp[t] += val;
    __syncthreads();
  }
  int run = tmp[t] - s;
#pragma unroll
  for (int i = 0; i < 4; i++) {
    if (base + i < n) rowptr[base + i] = run;
    run += v[i];
  }
  if (t == 255) bsum[blockIdx.x] = tmp[255];
}

__global__ __launch_bounds__(128) void scan_bsums(int* __restrict__ bsum, int nb) {
  __shared__ int tmp[128];
  int t = threadIdx.x;
  int v = (t < nb) ? bsum[t] : 0;
  tmp[t] = v;
  __syncthreads();
#pragma unroll
  for (int off = 1; off < 128; off <<= 1) {
    int val = (t >= off) ? tmp[t - off] : 0;
    __syncthreads();
    tmp[t] += val;
    __syncthreads();
  }
  if (t < nb) bsum[t] = tmp[t] - v;
}

__global__ __launch_bounds__(256) void scan_add(int* __restrict__ out,
                                                const int* __restrict__ bsum, int n) {
  int i = blockIdx.x * 256 + threadIdx.x;
  if (i < n) out[i] += bsum[i / SCAN_BLK];
}

// ---- CSR placement, atomic-free ----
__global__ __launch_bounds__(256) void gcn_place(const int* __restrict__ src,
                                                 const int* __restrict__ dst,
                                                 const int* __restrict__ rowptr,
                                                 const int* __restrict__ rank,
                                                 int* __restrict__ col, int E) {
  int base = (blockIdx.x * 256 + threadIdx.x) * 4;
  if (base + 4 <= E) {
    int4 s4 = *(const int4*)(src + base);
    int4 d4 = *(const int4*)(dst + base);
    int4 r4 = *(const int4*)(rank + base);
    col[rowptr[d4.x] + r4.x] = s4.x;
    col[rowptr[d4.y] + r4.y] = s4.y;
    col[rowptr[d4.z] + r4.z] = s4.z;
    col[rowptr[d4.w] + r4.w] = s4.w;
  } else {
    for (int e = base; e < E; e++) col[rowptr[dst[e]] + rank[e]] = src[e];
  }
}

__device__ inline void acc8h(float* a, uint4 r, float nn) {
  const __half2* hp = reinterpret_cast<const __half2*>(&r);
#pragma unroll
  for (int i = 0; i < 4; i++) {
    float2 f = __half22float2(hp[i]);
    a[2 * i] += nn * f.x;
    a[2 * i + 1] += nn * f.y;
  }
}

// ---- pull 64 feats (fp16 rows, out_norm applied per gathered row) ----
// 1 wave/node; sub = lane>>3 (8 edge slots), fq = lane&7 (16B chunk of 128B row)
__global__ __launch_bounds__(256) void gcn_pull64(const int* __restrict__ rowptr,
                                                  const int* __restrict__ deg,
                                                  const int* __restrict__ col,
                                                  const __half* __restrict__ h,
                                                  const float* __restrict__ out_norm,
                                                  float* __restrict__ agg, int n) {
  int t = threadIdx.x;
  int node = blockIdx.x * 4 + (t >> 6);
  if (node >= n) return;
  int l = t & 63;
  int sub = l >> 3, fq = l & 7;
  int beg = rowptr[node];
  int end = beg + deg[node];
  float a0[8] = {0, 0, 0, 0, 0, 0, 0, 0};
  float a1[8] = {0, 0, 0, 0, 0, 0, 0, 0};
  int j = beg;
  for (; j + 16 <= end; j += 16) {
    int s0 = col[j + sub];
    int s1 = col[j + 8 + sub];
    float n0 = out_norm[s0], n1 = out_norm[s1];
    uint4 r0 = ((const uint4*)h)[(size_t)s0 * 8 + fq];
    uint4 r1 = ((const uint4*)h)[(size_t)s1 * 8 + fq];
    acc8h(a0, r0, n0);
    acc8h(a1, r1, n1);
  }
  for (; j < end; j += 8) {
    int jj = j + sub;
    if (jj < end) {
      int s = col[jj];
      float nn = out_norm[s];
      uint4 r = ((const uint4*)h)[(size_t)s * 8 + fq];
      acc8h(a0, r, nn);
    }
  }
  float acc[8];
#pragma unroll
  for (int i = 0; i < 8; i++) acc[i] = a0[i] + a1[i];
#pragma unroll
  for (int d = 8; d <= 32; d <<= 1) {
#pragma unroll
    for (int i = 0; i < 8; i++) acc[i] += __shfl_xor(acc[i], d);
  }
  if (sub == 0) {
    float4 o0 = {acc[0], acc[1], acc[2], acc[3]};
    float4 o1 = {acc[4], acc[5], acc[6], acc[7]};
    ((float4*)agg)[(size_t)node * 16 + fq * 2] = o0;
    ((float4*)agg)[(size_t)node * 16 + fq * 2 + 1] = o1;
  }
}

// ---- h2[N,32] = (relu(agg1*in_norm + b1) * out_norm) @ W2[64,32], fp16 out ----
__global__ __launch_bounds__(256) void gcn_xw2(const float* __restrict__ agg1,
                                               const float* __restrict__ W,
                                               const float* __restrict__ b1,
                                               const float* __restrict__ in_norm,
                                               const float* __restrict__ out_norm,
                                               __half* __restrict__ h2, int n) {
  __shared__ float Ws[64 * 32];
  __shared__ float xs[16 * 64];
  int t = threadIdx.x;
#pragma unroll
  for (int i = 0; i < 8; i++) Ws[i * 256 + t] = W[i * 256 + t];
  int row0 = blockIdx.x * 16;
#pragma unroll
  for (int i = 0; i < 4; i++) {
    int gi = i * 256 + t;
    int r = gi >> 6, k = gi & 63;
    int row = row0 + r;
    float v = 0.0f;
    if (row < n)
      v = fmaxf(agg1[(size_t)row * 64 + k] * in_norm[row] + b1[k], 0.0f) * out_norm[row];
    xs[gi] = v;
  }
  __syncthreads();
  int c = t & 31, rq = t >> 5;
  float acc0 = 0.f, acc1 = 0.f;
#pragma unroll 16
  for (int k = 0; k < 64; k++) {
    float w = Ws[k * 32 + c];
    acc0 += xs[rq * 64 + k] * w;
    acc1 += xs[(rq + 8) * 64 + k] * w;
  }
  int row = row0 + rq;
  if (row < n) h2[(size_t)row * 32 + c] = __float2half(acc0);
  row = row0 + rq + 8;
  if (row < n) h2[(size_t)row * 32 + c] = __float2half(acc1);
}

// ---- pull 32 feats (fp16 rows) + epilogue ----
// sub = lane>>3 (8 slots), fq = lane&7 (8B chunk = 4 halves of 64B row)
__global__ __launch_bounds__(256) void gcn_pull32(const int* __restrict__ rowptr,
                                                  const int* __restrict__ deg,
                                                  const int* __restrict__ col,
                                                  const __half* __restrict__ h,
                                                  const float* __restrict__ in_norm,
                                                  const float* __restrict__ b2,
                                                  float* __restrict__ out, int n) {
  int t = threadIdx.x;
  int node = blockIdx.x * 4 + (t >> 6);
  if (node >= n) return;
  int l = t & 63;
  int sub = l >> 3, fq = l & 7;
  int beg = rowptr[node];
  int end = beg + deg[node];
  float a0[4] = {0, 0, 0, 0}, a1[4] = {0, 0, 0, 0};
  int j = beg;
  for (; j + 16 <= end; j += 16) {
    int s0 = col[j + sub];
    int s1 = col[j + 8 + sub];
    uint2 r0 = ((const uint2*)h)[(size_t)s0 * 8 + fq];
    uint2 r1 = ((const uint2*)h)[(size_t)s1 * 8 + fq];
    const __half2* p0 = reinterpret_cast<const __half2*>(&r0);
    const __half2* p1 = reinterpret_cast<const __half2*>(&r1);
#pragma unroll
    for (int i = 0; i < 2; i++) {
      float2 f0 = __half22float2(p0[i]);
      float2 f1 = __half22float2(p1[i]);
      a0[2 * i] += f0.x; a0[2 * i + 1] += f0.y;
      a1[2 * i] += f1.x; a1[2 * i + 1] += f1.y;
    }
  }
  for (; j < end; j += 8) {
    int jj = j + sub;
    if (jj < end) {
      int s = col[jj];
      uint2 r = ((const uint2*)h)[(size_t)s * 8 + fq];
      const __half2* p = reinterpret_cast<const __half2*>(&r);
#pragma unroll
      for (int i = 0; i < 2; i++) {
        float2 f = __half22float2(p[i]);
        a0[2 * i] += f.x; a0[2 * i + 1] += f.y;
      }
    }
  }
  float acc[4];
#pragma unroll
  for (int i = 0; i < 4; i++) acc[i] = a0[i] + a1[i];
#pragma unroll
  for (int d = 8; d <= 32; d <<= 1) {
#pragma unroll
    for (int i = 0; i < 4; i++) acc[i] += __shfl_xor(acc[i], d);
  }
  if (sub == 0) {
    float s = in_norm[node];
    float4 bb = ((const float4*)b2)[fq];
    float4 o;
    o.x = acc[0] * s + bb.x;
    o.y = acc[1] * s + bb.y;
    o.z = acc[2] * s + bb.z;
    o.w = acc[3] * s + bb.w;
    ((float4*)out)[(size_t)node * 8 + fq] = o;
  }
}

extern "C" void kernel_launch(void* const* d_in, const int* in_sizes, int n_in,
                              void* d_out, int out_size, void* d_ws, size_t ws_size,
                              hipStream_t stream) {
  const float* x   = (const float*)d_in[0];
  const int*   src = (const int*)d_in[1];
  const int*   dst = (const int*)d_in[2];
  const float* W1  = (const float*)d_in[3];
  const float* b1  = (const float*)d_in[4];
  const float* W2  = (const float*)d_in[5];
  const float* b2  = (const float*)d_in[6];
  float* out = (float*)d_out;

  const int N = in_sizes[0] / 64;   // 100000
  const int E = in_sizes[1];        // 1600000
  const int NB = (N + SCAN_BLK - 1) / SCAN_BLK;

  int* hist_s = (int*)d_ws;                    // N (dense)
  int* hist_d = hist_s + N;                    // N (dense; doubles as deg)
  int* rowptr = hist_d + N;                    // N
  int* bsum   = rowptr + N;                    // 1024
  int* col    = bsum + 1024;                   // E
  float* out_norm = (float*)(col + E);         // N
  float* in_norm  = out_norm + N;              // N
  float* agg1     = in_norm + N;               // 64N floats (alias rank[E] ints)
  int*   rank     = (int*)agg1;                // dead before pull64 writes agg1
  __half* h1      = (__half*)(agg1 + (size_t)64 * N);  // 64N halves
  __half* h2      = h1;                        // h1 dead after pull64

  hipMemsetAsync(hist_s, 0, (size_t)2 * N * sizeof(int), stream);

  int GH = (E + 255) / 256;      // hist blocks
  int GX = (N + 15) / 16;        // xw1 blocks
  fused_hist_xw1<<<GH + GX, 256, 0, stream>>>(src, dst, hist_s, hist_d, rank,
                                              x, W1, h1, E, N, GH, GX);
  scan_local<<<NB, 256, 0, stream>>>(hist_d, hist_s, rowptr, bsum, out_norm, in_norm, N);
  scan_bsums<<<1, 128, 0, stream>>>(bsum, NB);
  scan_add<<<(N + 255) / 256, 256, 0, stream>>>(rowptr, bsum, N);
  int gE4 = (E / 4 + 255) / 256 + 1;
  gcn_place<<<gE4, 256, 0, stream>>>(src, dst, rowptr, rank, col, E);
  gcn_pull64<<<(N + 3) / 4, 256, 0, stream>>>(rowptr, hist_d, col, h1, out_norm, agg1, N);
  gcn_xw2<<<(N + 15) / 16, 256, 0, stream>>>(agg1, W2, b1, in_norm, out_norm, h2, N);
  gcn_pull32<<<(N + 3) / 4, 256, 0, stream>>>(rowptr, hist_d, col, h2, in_norm, b2, out, N);
}

// Round 6
// 323.809 us; speedup vs baseline: 1.2850x; 1.0408x over previous
//
#include <hip/hip_runtime.h>
#include <hip/hip_fp16.h>

// GCN 2-layer GraphConv (norm='both'), fp32 in/out, fp16 intermediates.
// Round 6: two atomic shadows — K1(hist_d+rank || xw1), K2(hist_s || place);
//          pull64 fused with xw2 (LDS row staging, no agg1 round-trip);
//          out_norm computed on the fly from hist_s.
//
// ws: int hist_s[N] | hist_d[N](=deg) | rowptr[N] | bsum[1024] | col[E] | rank[E]
//     float in_norm[N]
//     half h1[64N] | h2[32N]

#define SCAN_BLK 1024

// ---- K1: hist_d + rank (even blocks) || h1 = x @ W1 unscaled (odd blocks) ----
__global__ __launch_bounds__(256) void k1_histd_xw1(
    const int* __restrict__ dst, int* __restrict__ hist_d, int* __restrict__ rank,
    const float* __restrict__ x, const float* __restrict__ W,
    __half* __restrict__ h1, int E, int n, int GH, int GX) {
  __shared__ float Ws[64 * 64];
  __shared__ float xs[16 * 64];
  int bid = blockIdx.x;
  int Mn = (GH < GX) ? GH : GX;
  bool isHist;
  int idx;
  if (bid < 2 * Mn) { isHist = !(bid & 1); idx = bid >> 1; }
  else               { isHist = (GH > GX); idx = bid - 2 * Mn + Mn; }

  if (isHist) {
    int e = idx * 256 + threadIdx.x;
    if (e < E) rank[e] = atomicAdd(&hist_d[dst[e]], 1);
    return;
  }
  int t = threadIdx.x;
#pragma unroll
  for (int i = 0; i < 16; i++) Ws[i * 256 + t] = W[i * 256 + t];
  int row0 = idx * 16;
#pragma unroll
  for (int i = 0; i < 4; i++) {
    int gi = i * 256 + t;
    int r = gi >> 6, k = gi & 63;
    int row = row0 + r;
    xs[gi] = (row < n) ? x[row * 64 + k] : 0.0f;
  }
  __syncthreads();
  int c = t & 63, rq = t >> 6;
  float acc[4] = {0.f, 0.f, 0.f, 0.f};
#pragma unroll 16
  for (int k = 0; k < 64; k++) {
    float w = Ws[k * 64 + c];
#pragma unroll
    for (int rr = 0; rr < 4; rr++) acc[rr] += xs[(rq + rr * 4) * 64 + k] * w;
  }
#pragma unroll
  for (int rr = 0; rr < 4; rr++) {
    int row = row0 + rq + rr * 4;
    if (row < n) h1[(size_t)row * 64 + c] = __float2half(acc[rr]);
  }
}

// ---- scan of hist_d -> rowptr, fused in_norm ----
__global__ __launch_bounds__(256) void scan_local(const int* __restrict__ hist_d,
                                                  int* __restrict__ rowptr,
                                                  int* __restrict__ bsum,
                                                  float* __restrict__ in_norm, int n) {
  __shared__ int tmp[256];
  int t = threadIdx.x;
  int base = blockIdx.x * SCAN_BLK + t * 4;
  int v[4], s = 0;
#pragma unroll
  for (int i = 0; i < 4; i++) {
    v[i] = (base + i < n) ? hist_d[base + i] : 0;
    s += v[i];
  }
#pragma unroll
  for (int i = 0; i < 4; i++)
    if (base + i < n) in_norm[base + i] = rsqrtf(fmaxf((float)v[i], 1.0f));
  tmp[t] = s;
  __syncthreads();
#pragma unroll
  for (int off = 1; off < 256; off <<= 1) {
    int val = (t >= off) ? tmp[t - off] : 0;
    __syncthreads();
    tmp[t] += val;
    __syncthreads();
  }
  int run = tmp[t] - s;
#pragma unroll
  for (int i = 0; i < 4; i++) {
    if (base + i < n) rowptr[base + i] = run;
    run += v[i];
  }
  if (t == 255) bsum[blockIdx.x] = tmp[255];
}

__global__ __launch_bounds__(128) void scan_bsums(int* __restrict__ bsum, int nb) {
  __shared__ int tmp[128];
  int t = threadIdx.x;
  int v = (t < nb) ? bsum[t] : 0;
  tmp[t] = v;
  __syncthreads();
#pragma unroll
  for (int off = 1; off < 128; off <<= 1) {
    int val = (t >= off) ? tmp[t - off] : 0;
    __syncthreads();
    tmp[t] += val;
    __syncthreads();
  }
  if (t < nb) bsum[t] = tmp[t] - v;
}

__global__ __launch_bounds__(256) void scan_add(int* __restrict__ out,
                                                const int* __restrict__ bsum, int n) {
  int i = blockIdx.x * 256 + threadIdx.x;
  if (i < n) out[i] += bsum[i / SCAN_BLK];
}

// ---- K2: hist_s atomics || CSR placement (place hides in atomic shadow) ----
__global__ __launch_bounds__(256) void k2_hists_place(
    const int* __restrict__ src, const int* __restrict__ dst,
    const int* __restrict__ rowptr, const int* __restrict__ rank,
    int* __restrict__ hist_s, int* __restrict__ col, int E) {
  int e = blockIdx.x * 256 + threadIdx.x;
  if (e < E) {
    int s = src[e];
    atomicAdd(&hist_s[s], 1);
    col[rowptr[dst[e]] + rank[e]] = s;
  }
}

__device__ inline void acc8h(float* a, uint4 r, float nn) {
  const __half2* hp = reinterpret_cast<const __half2*>(&r);
#pragma unroll
  for (int i = 0; i < 4; i++) {
    float2 f = __half22float2(hp[i]);
    a[2 * i] += nn * f.x;
    a[2 * i + 1] += nn * f.y;
  }
}

// ---- pull64 + fused xw2: per wave gather/reduce -> LDS row -> block @W2 ----
// wave w handles node blockIdx*4+w; sub = lane>>3 (8 edge slots), fq = lane&7.
__global__ __launch_bounds__(256) void pull64_xw2(
    const int* __restrict__ rowptr, const int* __restrict__ deg,
    const int* __restrict__ col, const __half* __restrict__ h1,
    const int* __restrict__ hist_s, const float* __restrict__ in_norm,
    const float* __restrict__ b1, const float* __restrict__ W2,
    __half* __restrict__ h2, int n) {
  __shared__ float W2s[64 * 32];
  __shared__ float xrow[4][64];
  int t = threadIdx.x;
#pragma unroll
  for (int i = 0; i < 8; i++) W2s[i * 256 + t] = W2[i * 256 + t];

  int w = t >> 6;
  int node = blockIdx.x * 4 + w;
  int l = t & 63;
  int sub = l >> 3, fq = l & 7;

  if (node < n) {
    int beg = rowptr[node];
    int end = beg + deg[node];
    float a0[8] = {0, 0, 0, 0, 0, 0, 0, 0};
    float a1[8] = {0, 0, 0, 0, 0, 0, 0, 0};
    int j = beg;
    for (; j + 16 <= end; j += 16) {
      int s0 = col[j + sub];
      int s1 = col[j + 8 + sub];
      float n0 = rsqrtf(fmaxf((float)hist_s[s0], 1.0f));
      float n1 = rsqrtf(fmaxf((float)hist_s[s1], 1.0f));
      uint4 r0 = ((const uint4*)h1)[(size_t)s0 * 8 + fq];
      uint4 r1 = ((const uint4*)h1)[(size_t)s1 * 8 + fq];
      acc8h(a0, r0, n0);
      acc8h(a1, r1, n1);
    }
    for (; j < end; j += 8) {
      int jj = j + sub;
      if (jj < end) {
        int s = col[jj];
        float nn = rsqrtf(fmaxf((float)hist_s[s], 1.0f));
        uint4 r = ((const uint4*)h1)[(size_t)s * 8 + fq];
        acc8h(a0, r, nn);
      }
    }
    float acc[8];
#pragma unroll
    for (int i = 0; i < 8; i++) acc[i] = a0[i] + a1[i];
#pragma unroll
    for (int d = 8; d <= 32; d <<= 1) {
#pragma unroll
      for (int i = 0; i < 8; i++) acc[i] += __shfl_xor(acc[i], d);
    }
    if (sub == 0) {
      float innv = in_norm[node];
      float onnv = rsqrtf(fmaxf((float)hist_s[node], 1.0f));
      float4 ba = ((const float4*)b1)[fq * 2];
      float4 bb = ((const float4*)b1)[fq * 2 + 1];
      float bv[8] = {ba.x, ba.y, ba.z, ba.w, bb.x, bb.y, bb.z, bb.w};
#pragma unroll
      for (int i = 0; i < 8; i++)
        xrow[w][fq * 8 + i] = fmaxf(acc[i] * innv + bv[i], 0.0f) * onnv;
    }
  }
  __syncthreads();
  // phase 2: h2[node,32] = xrow @ W2  (threads 0..127: w2=t>>5, c=t&31)
  if (t < 128) {
    int w2 = t >> 5, c = t & 31;
    int nd = blockIdx.x * 4 + w2;
    if (nd < n) {
      float dot = 0.f;
#pragma unroll 16
      for (int k = 0; k < 64; k++) dot += xrow[w2][k] * W2s[k * 32 + c];
      h2[(size_t)nd * 32 + c] = __float2half(dot);
    }
  }
}

// ---- pull 32 feats + epilogue: out = agg*in_norm + b2 ----
__global__ __launch_bounds__(256) void gcn_pull32(const int* __restrict__ rowptr,
                                                  const int* __restrict__ deg,
                                                  const int* __restrict__ col,
                                                  const __half* __restrict__ h,
                                                  const float* __restrict__ in_norm,
                                                  const float* __restrict__ b2,
                                                  float* __restrict__ out, int n) {
  int t = threadIdx.x;
  int node = blockIdx.x * 4 + (t >> 6);
  if (node >= n) return;
  int l = t & 63;
  int sub = l >> 3, fq = l & 7;
  int beg = rowptr[node];
  int end = beg + deg[node];
  float a0[4] = {0, 0, 0, 0}, a1[4] = {0, 0, 0, 0};
  int j = beg;
  for (; j + 16 <= end; j += 16) {
    int s0 = col[j + sub];
    int s1 = col[j + 8 + sub];
    uint2 r0 = ((const uint2*)h)[(size_t)s0 * 8 + fq];
    uint2 r1 = ((const uint2*)h)[(size_t)s1 * 8 + fq];
    const __half2* p0 = reinterpret_cast<const __half2*>(&r0);
    const __half2* p1 = reinterpret_cast<const __half2*>(&r1);
#pragma unroll
    for (int i = 0; i < 2; i++) {
      float2 f0 = __half22float2(p0[i]);
      float2 f1 = __half22float2(p1[i]);
      a0[2 * i] += f0.x; a0[2 * i + 1] += f0.y;
      a1[2 * i] += f1.x; a1[2 * i + 1] += f1.y;
    }
  }
  for (; j < end; j += 8) {
    int jj = j + sub;
    if (jj < end) {
      int s = col[jj];
      uint2 r = ((const uint2*)h)[(size_t)s * 8 + fq];
      const __half2* p = reinterpret_cast<const __half2*>(&r);
#pragma unroll
      for (int i = 0; i < 2; i++) {
        float2 f = __half22float2(p[i]);
        a0[2 * i] += f.x; a0[2 * i + 1] += f.y;
      }
    }
  }
  float acc[4];
#pragma unroll
  for (int i = 0; i < 4; i++) acc[i] = a0[i] + a1[i];
#pragma unroll
  for (int d = 8; d <= 32; d <<= 1) {
#pragma unroll
    for (int i = 0; i < 4; i++) acc[i] += __shfl_xor(acc[i], d);
  }
  if (sub == 0) {
    float s = in_norm[node];
    float4 bb = ((const float4*)b2)[fq];
    float4 o;
    o.x = acc[0] * s + bb.x;
    o.y = acc[1] * s + bb.y;
    o.z = acc[2] * s + bb.z;
    o.w = acc[3] * s + bb.w;
    ((float4*)out)[(size_t)node * 8 + fq] = o;
  }
}

extern "C" void kernel_launch(void* const* d_in, const int* in_sizes, int n_in,
                              void* d_out, int out_size, void* d_ws, size_t ws_size,
                              hipStream_t stream) {
  const float* x   = (const float*)d_in[0];
  const int*   src = (const int*)d_in[1];
  const int*   dst = (const int*)d_in[2];
  const float* W1  = (const float*)d_in[3];
  const float* b1  = (const float*)d_in[4];
  const float* W2  = (const float*)d_in[5];
  const float* b2  = (const float*)d_in[6];
  float* out = (float*)d_out;

  const int N = in_sizes[0] / 64;   // 100000
  const int E = in_sizes[1];        // 1600000
  const int NB = (N + SCAN_BLK - 1) / SCAN_BLK;

  int* hist_s = (int*)d_ws;                    // N
  int* hist_d = hist_s + N;                    // N (doubles as deg)
  int* rowptr = hist_d + N;                    // N
  int* bsum   = rowptr + N;                    // 1024
  int* col    = bsum + 1024;                   // E
  int* rank   = col + E;                       // E
  float* in_norm = (float*)(rank + E);         // N
  __half* h1  = (__half*)(in_norm + N);        // 64N halves
  __half* h2  = h1 + (size_t)64 * N;           // 32N halves (h1 live during pull64_xw2!)

  hipMemsetAsync(hist_s, 0, (size_t)2 * N * sizeof(int), stream);

  int GH = (E + 255) / 256;      // 6250
  int GX = (N + 15) / 16;        // 6250
  k1_histd_xw1<<<GH + GX, 256, 0, stream>>>(dst, hist_d, rank, x, W1, h1, E, N, GH, GX);
  scan_local<<<NB, 256, 0, stream>>>(hist_d, rowptr, bsum, in_norm, N);
  scan_bsums<<<1, 128, 0, stream>>>(bsum, NB);
  scan_add<<<(N + 255) / 256, 256, 0, stream>>>(rowptr, bsum, N);
  k2_hists_place<<<GH, 256, 0, stream>>>(src, dst, rowptr, rank, hist_s, col, E);
  pull64_xw2<<<(N + 3) / 4, 256, 0, stream>>>(rowptr, hist_d, col, h1, hist_s,
                                              in_norm, b1, W2, h2, N);
  gcn_pull32<<<(N + 3) / 4, 256, 0, stream>>>(rowptr, hist_d, col, h2, in_norm, b2, out, N);
}